// Round 11
// baseline (50.681 us; speedup 1.0000x reference)
//
#include <hip/hip_runtime.h>
#include <stdint.h>

#define S 2048
#define DHEAD 64
#define CDIM 256
#define NBATCH 8
#define NSTEP 32 // S/64 K-steps in gemm
#define SMT 8    // m-tiles per scores block

typedef __attribute__((ext_vector_type(4))) float f32x4;
typedef __attribute__((ext_vector_type(8))) short s16x8;
typedef __attribute__((ext_vector_type(8))) _Float16 f16x8;
typedef __attribute__((ext_vector_type(4))) unsigned short u16x4;

static __device__ __forceinline__ unsigned short f2bf(float f) {
    unsigned int u = __builtin_bit_cast(unsigned int, f);
    unsigned int r = (u + 0x7FFFu + ((u >> 16) & 1u)) >> 16;  // RNE
    return (unsigned short)r;
}
static __device__ __forceinline__ unsigned short f2h(float f) {
    _Float16 h = (_Float16)f;
    return __builtin_bit_cast(unsigned short, h);
}
static __device__ __forceinline__ float bf2f(unsigned short u) {
    return __builtin_bit_cast(float, (unsigned int)u << 16);
}

// async global->LDS, 16B per lane; LDS dest = wave-uniform base + lane*16
#define GLOAD16(g, l)                                                              \
    __builtin_amdgcn_global_load_lds(                                              \
        (const __attribute__((address_space(1))) void*)(g),                        \
        (__attribute__((address_space(3))) void*)(l), 16, 0, 0)

// ---- kernel 0: a->bf16, b->f16, c->f16 -------------------------------------
__global__ __launch_bounds__(256) void cvt_kernel(
    const float* __restrict__ a, const float* __restrict__ b, const float* __restrict__ c,
    unsigned short* __restrict__ a16, unsigned short* __restrict__ b16,
    unsigned short* __restrict__ c16)
{
    const int na4 = NBATCH * CDIM * S / 4;
    const int nbc4 = NBATCH * S * DHEAD / 4;
    int i0 = blockIdx.x * 256 + threadIdx.x;
    int stride = gridDim.x * 256;
    for (int i = i0; i < na4; i += stride) {
        f32x4 v = ((const f32x4*)a)[i];
        u16x4 o; o.x = f2bf(v.x); o.y = f2bf(v.y); o.z = f2bf(v.z); o.w = f2bf(v.w);
        ((u16x4*)a16)[i] = o;
    }
    for (int i = i0; i < nbc4; i += stride) {
        f32x4 v = ((const f32x4*)b)[i];
        u16x4 o; o.x = f2h(v.x); o.y = f2h(v.y); o.z = f2h(v.z); o.w = f2h(v.w);
        ((u16x4*)b16)[i] = o;
        f32x4 u = ((const f32x4*)c)[i];
        u16x4 p; p.x = f2h(u.x); p.y = f2h(u.y); p.z = f2h(u.z); p.w = f2h(u.w);
        ((u16x4*)c16)[i] = p;
    }
}

// ---- kernel 1: E = exp(b @ c^T), pipelined multi-m-tile (T3/T4/T5) ---------
// Block = 64 n-rows x 8 m-tiles(128). b staged once; c double-buffered with
// distance-1 DMA prefetch + counted vmcnt(4) (in-order retirement: newest 4
// ops are always the just-issued next-tile loads, so everything older —
// current tile's loads and prior flush stores — is drained). 2 blocks/CU.
__global__ __launch_bounds__(256, 2) void scores_kernel(
    const unsigned short* __restrict__ B16, const unsigned short* __restrict__ C16,
    unsigned short* __restrict__ E, float* __restrict__ Lp, int b0, int nb)
{
    const int bid = blockIdx.x;
    int lb, idx;
    if (nb == 8) { lb = bid & 7; idx = bid >> 3; }
    else { lb = bid / 64; idx = bid - lb * 64; }
    const int gb = b0 + lb;
    const int nt = idx >> 1, mh = idx & 1;   // mh-pairs adjacent -> share b rows in L2
    const int n0 = nt * 64;
    const int mbase = mh * (SMT * 128);

    const unsigned short* __restrict__ bp = B16 + (size_t)gb * S * DHEAD;
    const unsigned short* __restrict__ cp = C16 + (size_t)gb * S * DHEAD;
    unsigned short* __restrict__ Ep = E + (size_t)lb * S * S;

    __shared__ unsigned short bs[64 * 64];      // f16 b rows (n), swizzled
    __shared__ unsigned short cs[2][128 * 64];  // f16 c rows (m), swizzled, dbuf
    __shared__ unsigned short es[64 * 136];     // bf16 E-tile [n][m], pad 136
    __shared__ float Lsh[4 * 32];

    const int tid = threadIdx.x;
    const int lane = tid & 63;
    const int w = tid >> 6;
    const int wr = w >> 1, wc = w & 1;
    const int q = lane >> 4, r15 = lane & 15;

    // staging decode (16B chunks, 8 per 64-short row; XOR pre-swizzle)
    int cRow[4], cOff[4], cR_[4], bRow[2], bOff[2], bR_[2];
    #pragma unroll
    for (int t = 0; t < 4; ++t) {
        int r = w + 4 * t, ch = r * 64 + lane;
        cR_[t] = r; cRow[t] = ch >> 3;
        cOff[t] = ((ch & 7) ^ ((ch >> 3) & 7)) * 8;
    }
    #pragma unroll
    for (int t = 0; t < 2; ++t) {
        int r = w + 4 * t, ch = r * 64 + lane;
        bR_[t] = r; bRow[t] = ch >> 3;
        bOff[t] = ((ch & 7) ^ ((ch >> 3) & 7)) * 8;
    }

#define SSTAGE_C(buf, m0)                                                          \
    {                                                                              \
        _Pragma("unroll")                                                          \
        for (int t = 0; t < 4; ++t)                                                \
            GLOAD16(cp + (size_t)((m0) + cRow[t]) * DHEAD + cOff[t],               \
                    &cs[buf][cR_[t] * 512]);                                       \
    }

    // prologue: b once + c tile 0
    #pragma unroll
    for (int t = 0; t < 2; ++t)
        GLOAD16(bp + (size_t)(n0 + bRow[t]) * DHEAD + bOff[t], &bs[bR_[t] * 512]);
    SSTAGE_C(0, mbase);

    float sj[2] = {0.f, 0.f};

    #pragma unroll
    for (int mt = 0; mt < SMT; ++mt) {
        const int cur = mt & 1;
        const int m0 = mbase + mt * 128;
        if (mt < SMT - 1) {
            SSTAGE_C(cur ^ 1, m0 + 128);
            asm volatile("s_waitcnt vmcnt(4)" ::: "memory");
        } else {
            asm volatile("s_waitcnt vmcnt(0)" ::: "memory");
        }
        __builtin_amdgcn_sched_barrier(0);
        __builtin_amdgcn_s_barrier();   // cs[cur] (and bs on mt=0) ready
        __builtin_amdgcn_sched_barrier(0);

        // scores MFMA: D[m][n]; wave = (wr: m 64-half, wc: n 32-half)
        f32x4 acc[4][2] = {};
        #pragma unroll
        for (int kk = 0; kk < 2; ++kk) {
            const int sz = ((kk * 4 + q) ^ (r15 & 7)) * 8;
            f16x8 af[4], bf[2];
            #pragma unroll
            for (int i = 0; i < 4; ++i)
                af[i] = *(const f16x8*)&cs[cur][(wr * 64 + i * 16 + r15) * 64 + sz];
            #pragma unroll
            for (int j = 0; j < 2; ++j)
                bf[j] = *(const f16x8*)&bs[(wc * 32 + j * 16 + r15) * 64 + sz];
            __builtin_amdgcn_s_setprio(1);
            #pragma unroll
            for (int i = 0; i < 4; ++i)
                #pragma unroll
                for (int j = 0; j < 2; ++j)
                    acc[i][j] = __builtin_amdgcn_mfma_f32_16x16x32_f16(af[i], bf[j], acc[i][j], 0, 0, 0);
            __builtin_amdgcn_s_setprio(0);
        }

        // exp + pack + row-sum partials
        u16x4 pk[4][2];
        #pragma unroll
        for (int i = 0; i < 4; ++i)
            #pragma unroll
            for (int j = 0; j < 2; ++j) {
                float e0 = __expf(acc[i][j][0]);
                float e1 = __expf(acc[i][j][1]);
                float e2 = __expf(acc[i][j][2]);
                float e3 = __expf(acc[i][j][3]);
                sj[j] += (e0 + e1) + (e2 + e3);
                pk[i][j].x = f2bf(e0); pk[i][j].y = f2bf(e1);
                pk[i][j].z = f2bf(e2); pk[i][j].w = f2bf(e3);
            }

        __syncthreads();  // prior flush's es ds_reads retired
        #pragma unroll
        for (int i = 0; i < 4; ++i)
            #pragma unroll
            for (int j = 0; j < 2; ++j) {
                int nl = wc * 32 + j * 16 + r15;
                int ml = wr * 64 + i * 16 + q * 4;
                *(u16x4*)&es[nl * 136 + ml] = pk[i][j];
            }
        __syncthreads();  // es visible

        // coalesced flush es -> E[n][m] (fire-and-forget stores)
        #pragma unroll
        for (int t = 0; t < 4; ++t) {
            int ch = tid + 256 * t;
            int row = ch >> 4, off = ch & 15;
            f32x4 v = *(const f32x4*)&es[row * 136 + off * 8];
            *(f32x4*)&Ep[(size_t)(n0 + row) * S + m0 + off * 8] = v;
        }
    }
#undef SSTAGE_C

    // reduce L over q groups; publish per-(mh) partials
    #pragma unroll
    for (int j = 0; j < 2; ++j) {
        sj[j] += __shfl_xor(sj[j], 16);
        sj[j] += __shfl_xor(sj[j], 32);
    }
    if (lane < 16) {
        Lsh[w * 32 + r15] = sj[0];
        Lsh[w * 32 + 16 + r15] = sj[1];
    }
    __syncthreads();
    if (tid < 64) {
        int wcn = tid >> 5, rem = tid & 31;  // rem = j*16 + r15
        float s = Lsh[wcn * 32 + rem] + Lsh[(2 + wcn) * 32 + rem];
        Lp[((size_t)lb * 2 + mh) * S + n0 + tid] = s;
    }
}

// staging decode shared by both gemm variants
#define GEMM_DECODE()                                                             \
    const int tid = threadIdx.x;                                                  \
    const int lane = tid & 63;                                                    \
    const int w = tid >> 6;                                                       \
    const int wr = w >> 1, wc = w & 1;                                            \
    const int q = lane >> 4, r15 = lane & 15;                                     \
    int aRow[4], aOff[4], aR_[4], bRow[2], bOff[2], bR_[2];                       \
    _Pragma("unroll")                                                             \
    for (int t = 0; t < 4; ++t) {                                                 \
        int r = w + 4 * t, ch = r * 64 + lane;                                    \
        aR_[t] = r; aRow[t] = ch >> 3;                                            \
        aOff[t] = ((ch & 7) ^ ((ch >> 3) & 7)) * 8;                               \
    }                                                                             \
    _Pragma("unroll")                                                             \
    for (int t = 0; t < 2; ++t) {                                                 \
        int r = w + 4 * t, ch = r * 64 + lane;                                    \
        bR_[t] = r; bRow[t] = ch >> 3;                                            \
        bOff[t] = ((ch & 7) ^ ((ch >> 3) & 7)) * 8;                               \
    }

#define STAGEP(bufA, bufB, k0)                                                    \
    {                                                                             \
        _Pragma("unroll")                                                         \
        for (int t = 0; t < 4; ++t)                                               \
            GLOAD16(Ap + (size_t)(c0 + aRow[t]) * S + (k0) + aOff[t],             \
                    (bufA) + aR_[t] * 512);                                       \
        _Pragma("unroll")                                                         \
        for (int t = 0; t < 2; ++t)                                               \
            GLOAD16(Bp + (size_t)(n0 + bRow[t]) * S + (k0) + bOff[t],             \
                    (bufB) + bR_[t] * 512);                                       \
    }

#define GEMM_EPILOGUE()                                                           \
    float rcpL[2];                                                                \
    _Pragma("unroll")                                                             \
    for (int j = 0; j < 2; ++j) {                                                 \
        int n = n0 + wc * 32 + j * 16 + r15;                                      \
        float s = Lp[(size_t)lb * 2 * S + n] + Lp[((size_t)lb * 2 + 1) * S + n]; \
        rcpL[j] = 1.0f / s;                                                       \
    }                                                                             \
    _Pragma("unroll")                                                             \
    for (int i = 0; i < 4; ++i) {                                                 \
        _Pragma("unroll")                                                         \
        for (int rr = 0; rr < 4; ++rr) {                                          \
            int cc = c0 + wr * 64 + i * 16 + q * 4 + rr;                          \
            size_t base = (size_t)cc * S;                                         \
            _Pragma("unroll")                                                     \
            for (int j = 0; j < 2; ++j) {                                         \
                int n = n0 + wc * 32 + j * 16 + r15;                              \
                op[base + n] = acc[i][j][rr] * rcpL[j] + bf2f(Ap[base + n]);      \
            }                                                                     \
        }                                                                         \
    }

// ---- kernel 2 (primary): 3-buffer, counted-vmcnt, raw barriers (R10) -------
__global__ __launch_bounds__(256, 2) void gemm_kernel3(
    const unsigned short* __restrict__ a16, const unsigned short* __restrict__ E,
    const float* __restrict__ Lp, float* __restrict__ out, int b0, int nb)
{
    const int bid = blockIdx.x;
    int lb, idx;
    if (nb == 8) { lb = bid & 7; idx = bid >> 3; }
    else { lb = bid / 64; idx = bid - lb * 64; }
    const int gb = b0 + lb;
    const int nt = idx >> 1, ct = idx & 1;
    const int n0 = nt * 64, c0 = ct * 128;

    const unsigned short* __restrict__ Ap = a16 + (size_t)gb * CDIM * S;
    const unsigned short* __restrict__ Bp = E + (size_t)lb * S * S;
    float* __restrict__ op = out + (size_t)gb * CDIM * S;

    extern __shared__ char gsm[];
    unsigned short* As[3];
    unsigned short* Bs[3];
    #pragma unroll
    for (int u = 0; u < 3; ++u) {
        As[u] = (unsigned short*)gsm + u * (128 * 64 + 64 * 64);
        Bs[u] = As[u] + 128 * 64;
    }

    GEMM_DECODE();

    f32x4 acc[4][2] = {};

    STAGEP(As[0], Bs[0], 0);
    STAGEP(As[1], Bs[1], 64);

    const int sw0 = (q ^ (r15 & 7)) * 8;
    const int sw1 = ((4 + q) ^ (r15 & 7)) * 8;

    #pragma unroll
    for (int kt = 0; kt < NSTEP; ++kt) {
        const int cur = kt % 3;
        if (kt <= NSTEP - 3) {
            STAGEP(As[(kt + 2) % 3], Bs[(kt + 2) % 3], (kt + 2) * 64);
            asm volatile("s_waitcnt vmcnt(12)" ::: "memory");
        } else if (kt == NSTEP - 2) {
            asm volatile("s_waitcnt vmcnt(6)" ::: "memory");
        } else {
            asm volatile("s_waitcnt vmcnt(0)" ::: "memory");
        }
        __builtin_amdgcn_sched_barrier(0);
        __builtin_amdgcn_s_barrier();
        __builtin_amdgcn_sched_barrier(0);

        const unsigned short* Ar = As[cur];
        const unsigned short* Br = Bs[cur];
        #pragma unroll
        for (int kk = 0; kk < 2; ++kk) {
            const int sz = kk ? sw1 : sw0;
            s16x8 af[4], bf[2];
            #pragma unroll
            for (int i = 0; i < 4; ++i)
                af[i] = *(const s16x8*)&Ar[(wr * 64 + i * 16 + r15) * 64 + sz];
            #pragma unroll
            for (int j = 0; j < 2; ++j)
                bf[j] = *(const s16x8*)&Br[(wc * 32 + j * 16 + r15) * 64 + sz];
            __builtin_amdgcn_s_setprio(1);
            #pragma unroll
            for (int i = 0; i < 4; ++i)
                #pragma unroll
                for (int j = 0; j < 2; ++j)
                    acc[i][j] = __builtin_amdgcn_mfma_f32_16x16x32_bf16(af[i], bf[j], acc[i][j], 0, 0, 0);
            __builtin_amdgcn_s_setprio(0);
        }

        __builtin_amdgcn_sched_barrier(0);
        __builtin_amdgcn_s_barrier();
    }

    GEMM_EPILOGUE();
}

// ---- kernel 2 (fallback): 2-buffer __syncthreads version -------------------
__global__ __launch_bounds__(256, 2) void gemm_kernel2(
    const unsigned short* __restrict__ a16, const unsigned short* __restrict__ E,
    const float* __restrict__ Lp, float* __restrict__ out, int b0, int nb)
{
    const int bid = blockIdx.x;
    int lb, idx;
    if (nb == 8) { lb = bid & 7; idx = bid >> 3; }
    else { lb = bid / 64; idx = bid - lb * 64; }
    const int gb = b0 + lb;
    const int nt = idx >> 1, ct = idx & 1;
    const int n0 = nt * 64, c0 = ct * 128;

    const unsigned short* __restrict__ Ap = a16 + (size_t)gb * CDIM * S;
    const unsigned short* __restrict__ Bp = E + (size_t)lb * S * S;
    float* __restrict__ op = out + (size_t)gb * CDIM * S;

    __shared__ unsigned short AsS[2][128 * 64];
    __shared__ unsigned short BsS[2][64 * 64];

    GEMM_DECODE();

    f32x4 acc[4][2] = {};

    STAGEP(AsS[0], BsS[0], 0);
    __syncthreads();

    const int sw0 = (q ^ (r15 & 7)) * 8;
    const int sw1 = ((4 + q) ^ (r15 & 7)) * 8;

    #pragma unroll 2
    for (int kt = 0; kt < NSTEP; ++kt) {
        const int cur = kt & 1;
        if (kt < NSTEP - 1) STAGEP(AsS[cur ^ 1], BsS[cur ^ 1], (kt + 1) * 64);

        #pragma unroll
        for (int kk = 0; kk < 2; ++kk) {
            const int sz = kk ? sw1 : sw0;
            s16x8 af[4], bf[2];
            #pragma unroll
            for (int i = 0; i < 4; ++i)
                af[i] = *(const s16x8*)&AsS[cur][(wr * 64 + i * 16 + r15) * 64 + sz];
            #pragma unroll
            for (int j = 0; j < 2; ++j)
                bf[j] = *(const s16x8*)&BsS[cur][(wc * 32 + j * 16 + r15) * 64 + sz];
            #pragma unroll
            for (int i = 0; i < 4; ++i)
                #pragma unroll
                for (int j = 0; j < 2; ++j)
                    acc[i][j] = __builtin_amdgcn_mfma_f32_16x16x32_bf16(af[i], bf[j], acc[i][j], 0, 0, 0);
        }
        __syncthreads();
    }

    GEMM_EPILOGUE();
}

// ---- launch ----------------------------------------------------------------
extern "C" void kernel_launch(void* const* d_in, const int* in_sizes, int n_in,
                              void* d_out, int out_size, void* d_ws, size_t ws_size,
                              hipStream_t stream) {
    const float* a = (const float*)d_in[0];
    const float* b = (const float*)d_in[1];
    const float* c = (const float*)d_in[2];
    float* out = (float*)d_out;

    const size_t a16_bytes = (size_t)NBATCH * CDIM * S * 2;    // 8 MB
    const size_t bc_bytes = (size_t)NBATCH * S * DHEAD * 2;    // 2 MB each
    const size_t head = a16_bytes + 2 * bc_bytes;              // 12 MB
    const size_t perb = (size_t)S * S * 2 + (size_t)2 * S * 4;
    int G = 1;
    if (ws_size > head + perb) {
        size_t g = (ws_size - head) / perb;
        G = (g >= NBATCH) ? NBATCH : (int)g;
        if (G < 1) G = 1;
    }
    unsigned short* a16 = (unsigned short*)d_ws;
    unsigned short* b16 = (unsigned short*)((char*)d_ws + a16_bytes);
    unsigned short* c16 = (unsigned short*)((char*)d_ws + a16_bytes + bc_bytes);
    unsigned short* E = (unsigned short*)((char*)d_ws + head);
    float* Lp = (float*)((char*)d_ws + head + (size_t)G * S * S * 2);

    const int gemm_lds3 = 3 * (128 * 64 + 64 * 64) * 2;  // 73728 B
    hipError_t attr_ok = hipFuncSetAttribute(
        reinterpret_cast<const void*>(gemm_kernel3),
        hipFuncAttributeMaxDynamicSharedMemorySize, gemm_lds3);

    cvt_kernel<<<1024, 256, 0, stream>>>(a, b, c, a16, b16, c16);

    for (int b0 = 0; b0 < NBATCH; b0 += G) {
        int nb = (NBATCH - b0 < G) ? (NBATCH - b0) : G;
        scores_kernel<<<64 * nb, 256, 0, stream>>>(b16, c16, E, Lp, b0, nb);
        if (attr_ok == hipSuccess)
            gemm_kernel3<<<64 * nb, 256, gemm_lds3, stream>>>(a16, E, Lp, out, b0, nb);
        else
            gemm_kernel2<<<64 * nb, 256, 0, stream>>>(a16, E, Lp, out, b0, nb);
    }
}